// Round 2
// baseline (82279.523 us; speedup 1.0000x reference)
//
#include <hip/hip_runtime.h>
#include <hip/hip_bf16.h>
#include <cstdint>
#include <cstddef>

// Problem constants
constexpr int Bb = 64, TXc = 512, TYc = 256, Vc = 10000;
// DE=256, HE=256, HD=512, AU=256, AT=256

// ---------------- workspace layout (floats) ----------------
constexpr size_t OFF_BAR   = 0;                       // 256 ints for barriers
constexpr size_t OFF_ENC_H = 256;                     // [2 dir][2 buf][256u*64b]
constexpr size_t OFF_ENC_C = OFF_ENC_H + 65536;       // [2 dir][16384]
constexpr size_t OFF_DEC_H = OFF_ENC_C + 32768;       // [2 buf][512u*64b]
constexpr size_t OFF_DEC_C = OFF_DEC_H + 65536;       // [32768]
constexpr size_t OFF_ATTN  = OFF_DEC_C + 32768;       // [256a*64b]
constexpr size_t SMALL_END = OFF_ATTN + 16384;        // zero-init region end
constexpr size_t OFF_ENCT  = SMALL_END;               // [512t][256k][64b]
constexpr size_t OFF_DECT  = OFF_ENCT + 8388608;      // [256t][256k][64b]
constexpr size_t OFF_MEM   = OFF_DECT + 4194304;      // [64b][512s][512c]
constexpr size_t OFF_KEYS  = OFF_MEM + 16777216;      // [64b][512s][256a]
constexpr size_t OFF_AALL  = OFF_KEYS + 8388608;      // [64b][256t][256a]
constexpr size_t OFF_SCORE = OFF_AALL + 4194304;      // [64b][512s]
constexpr size_t WS_FLOATS = OFF_SCORE + 32768;       // ~161 MB

// ---------------- device helpers ----------------
__device__ __forceinline__ float sigm_fast(float x) {
  return __fdividef(1.0f, 1.0f + __expf(-x));
}
__device__ __forceinline__ float tanh_fast(float x) {
  x = fminf(fmaxf(x, -15.0f), 15.0f);
  float t = __expf(2.0f * x);
  return __fdividef(t - 1.0f, t + 1.0f);
}
// precise versions for the recurrent cell (cheap there, minimizes drift)
__device__ __forceinline__ float sigm_p(float x) { return 1.0f / (1.0f + expf(-x)); }

// grid barrier: sense-reversing, agent scope. All `nb` blocks must be resident.
__device__ __forceinline__ void gbar(int* cnt, int* gen, int nb) {
  __syncthreads();
  if (threadIdx.x == 0) {
    __threadfence();
    int g = __hip_atomic_load(gen, __ATOMIC_RELAXED, __HIP_MEMORY_SCOPE_AGENT);
    if (__hip_atomic_fetch_add(cnt, 1, __ATOMIC_ACQ_REL, __HIP_MEMORY_SCOPE_AGENT) == nb - 1) {
      __hip_atomic_store(cnt, 0, __ATOMIC_RELAXED, __HIP_MEMORY_SCOPE_AGENT);
      __hip_atomic_store(gen, g + 1, __ATOMIC_RELEASE, __HIP_MEMORY_SCOPE_AGENT);
    } else {
      while (__hip_atomic_load(gen, __ATOMIC_ACQUIRE, __HIP_MEMORY_SCOPE_AGENT) == g) {
        __builtin_amdgcn_s_sleep(1);
      }
    }
    __threadfence();
  }
  __syncthreads();
}

// ---------------- embedding gather, transposed [t][k][b] ----------------
__global__ void k_gatherT(const int* __restrict__ idx, const float* __restrict__ E,
                          float* __restrict__ outT, int T) {
  int gid = blockIdx.x * 256 + threadIdx.x;
  int b = gid & 63;
  int k = (gid >> 6) & 255;
  int t = gid >> 14;
  if (t >= T) return;
  int row = idx[b * T + t];
  outT[(size_t)(t * 256 + k) * 64 + b] = E[(size_t)row * 256 + k];
}

// ---------------- bidirectional encoder, persistent ----------------
// grid = 128 blocks (dir 0..1 x ug 0..63), 256 threads = 4 usub-waves x 64 b
__global__ __launch_bounds__(256, 1) void k_encoder(
    const float* __restrict__ encT, const float* __restrict__ Wf, const float* __restrict__ bf,
    const float* __restrict__ Wb, const float* __restrict__ bb, float* __restrict__ ws) {
  int* bar = (int*)ws;
  int blk = blockIdx.x;
  int dir = blk >> 6;
  int ug = blk & 63;
  int tid = threadIdx.x;
  int usub = tid >> 6, b = tid & 63;
  int u = (ug << 2) + usub;
  const float* W = dir ? Wb : Wf;
  const float* bias = dir ? bb : bf;
  float* hT = ws + OFF_ENC_H + dir * 32768;  // [2][16384]
  float* cT = ws + OFF_ENC_C + dir * 16384;
  float* mem = ws + OFF_MEM;

  __shared__ float Wl[512 * 16];  // 32 KB: [k][usub*4+j]
  for (int i = tid; i < 512 * 16; i += 256) {
    int k = i >> 4, c = i & 15;
    Wl[i] = W[(size_t)k * 1024 + (ug << 2) + (c >> 2) + ((c & 3) << 8)];
  }
  float bj0 = bias[u], bj1 = bias[u + 256], bj2 = bias[u + 512], bj3 = bias[u + 768];
  __syncthreads();

  const float* wl = Wl + (usub << 2);
  for (int t = 0; t < TXc; ++t) {
    int tt = dir ? (TXc - 1 - t) : t;
    const float* hprev = hT + (t & 1) * 16384;
    float a0 = bj0, a1 = bj1, a2 = bj2, a3 = bj3;
    const float* xp = encT + (size_t)tt * 256 * 64 + b;
#pragma unroll 8
    for (int k = 0; k < 256; ++k) {
      float xv = xp[k << 6];
      float4 w = *(const float4*)(wl + (k << 4));
      a0 = fmaf(xv, w.x, a0); a1 = fmaf(xv, w.y, a1);
      a2 = fmaf(xv, w.z, a2); a3 = fmaf(xv, w.w, a3);
    }
#pragma unroll 8
    for (int k = 0; k < 256; ++k) {
      float hv = hprev[(k << 6) + b];
      float4 w = *(const float4*)(wl + ((256 + k) << 4));
      a0 = fmaf(hv, w.x, a0); a1 = fmaf(hv, w.y, a1);
      a2 = fmaf(hv, w.z, a2); a3 = fmaf(hv, w.w, a3);
    }
    float cold = cT[(u << 6) + b];
    float ig = sigm_p(a0), jg = tanhf(a1), fg = sigm_p(a2 + 1.0f), og = sigm_p(a3);
    float cn = fmaf(cold, fg, ig * jg);
    float hn = tanhf(cn) * og;
    cT[(u << 6) + b] = cn;
    hT[((t + 1) & 1) * 16384 + (u << 6) + b] = hn;
    mem[((size_t)((b << 9) | tt) << 9) + (dir << 8) + u] = hn;
    gbar(bar, bar + 64, 128);
  }
}

// ---------------- decoder, persistent ----------------
// grid = 128 blocks, 256 threads
__global__ __launch_bounds__(256, 1) void k_decoder(
    const float* __restrict__ decT, const float* __restrict__ Wd, const float* __restrict__ bd,
    const float* __restrict__ Wq, const float* __restrict__ vatt,
    const float* __restrict__ Watt, const float* __restrict__ keys, float* __restrict__ ws) {
  int* bar = (int*)ws;
  int* cnt = bar + 128;
  int* gen = bar + 192;
  int blk = blockIdx.x, tid = threadIdx.x;
  float* hT = ws + OFF_DEC_H;
  float* cT = ws + OFF_DEC_C;
  float* attnT = ws + OFF_ATTN;
  float* mem = ws + OFF_MEM;
  float* score = ws + OFF_SCORE;
  float* aall = ws + OFF_AALL;

  int usub = tid >> 6, b1 = tid & 63;
  int u = (blk << 2) + usub;

  __shared__ float Wl[1024 * 16];  // 64 KB: W_dec slice [k][usub*4+j]
  __shared__ float pq[256], vl[256], sl[512], red[256], ctx[512];
  for (int i = tid; i < 1024 * 16; i += 256) {
    int k = i >> 4, c = i & 15;
    Wl[i] = Wd[(size_t)k * 2048 + (blk << 2) + (c >> 2) + ((c & 3) << 9)];
  }
  vl[tid] = vatt[tid];
  float bj0 = bd[u], bj1 = bd[u + 512], bj2 = bd[u + 1024], bj3 = bd[u + 1536];
  __syncthreads();

  const float* wl = Wl + (usub << 2);
  for (int t = 0; t < TYc; ++t) {
    int par = t & 1;
    const float* hprev = hT + par * 32768;
    float* hcur = hT + (par ^ 1) * 32768;
    // ---- S1: z = [x | attn | h] @ W_dec + b; LSTM cell
    {
      float a0 = bj0, a1 = bj1, a2 = bj2, a3 = bj3;
      const float* xp = decT + (size_t)t * 256 * 64 + b1;
#pragma unroll 8
      for (int k = 0; k < 256; ++k) {
        float xv = xp[k << 6];
        float4 w = *(const float4*)(wl + (k << 4));
        a0 = fmaf(xv, w.x, a0); a1 = fmaf(xv, w.y, a1);
        a2 = fmaf(xv, w.z, a2); a3 = fmaf(xv, w.w, a3);
      }
#pragma unroll 8
      for (int k = 0; k < 256; ++k) {
        float av = attnT[(k << 6) + b1];
        float4 w = *(const float4*)(wl + ((256 + k) << 4));
        a0 = fmaf(av, w.x, a0); a1 = fmaf(av, w.y, a1);
        a2 = fmaf(av, w.z, a2); a3 = fmaf(av, w.w, a3);
      }
#pragma unroll 8
      for (int k = 0; k < 512; ++k) {
        float hv = hprev[(k << 6) + b1];
        float4 w = *(const float4*)(wl + ((512 + k) << 4));
        a0 = fmaf(hv, w.x, a0); a1 = fmaf(hv, w.y, a1);
        a2 = fmaf(hv, w.z, a2); a3 = fmaf(hv, w.w, a3);
      }
      float cold = cT[(u << 6) + b1];
      float ig = sigm_p(a0), jg = tanhf(a1), fg = sigm_p(a2 + 1.0f), og = sigm_p(a3);
      float cn = fmaf(cold, fg, ig * jg);
      float hn = tanhf(cn) * og;
      cT[(u << 6) + b1] = cn;
      hcur[(u << 6) + b1] = hn;
    }
    gbar(cnt, gen, 128);
    // ---- S2: pq = h @ W_q (per-b, redundant x2); scores for 256 s each
    {
      int b = blk >> 1, sh = blk & 1;
      const float* hc = hcur + b;
      const float* wq = Wq + tid;
      float acc = 0.f;
#pragma unroll 8
      for (int k = 0; k < 512; ++k) acc = fmaf(hc[k << 6], wq[k << 8], acc);
      pq[tid] = acc;
      __syncthreads();
      int s = (sh << 8) + tid;
      const float* kp = keys + ((size_t)((b << 9) + s) << 8);
      float sc = 0.f;
#pragma unroll 4
      for (int a = 0; a < 256; ++a) sc = fmaf(tanh_fast(kp[a] + pq[a]), vl[a], sc);
      score[(b << 9) + s] = sc;
    }
    gbar(cnt, gen, 128);
    // ---- S3: softmax over s, context, attn_new (blocks 0..63, one per b)
    if (blk < 64) {
      int b = blk;
      float s0v = score[(b << 9) + tid];
      float s1v = score[(b << 9) + 256 + tid];
      red[tid] = fmaxf(s0v, s1v);
      __syncthreads();
#pragma unroll
      for (int off = 128; off > 0; off >>= 1) {
        if (tid < off) red[tid] = fmaxf(red[tid], red[tid + off]);
        __syncthreads();
      }
      float mx = red[0];
      __syncthreads();
      float p0 = __expf(s0v - mx), p1 = __expf(s1v - mx);
      sl[tid] = p0; sl[tid + 256] = p1;
      red[tid] = p0 + p1;
      __syncthreads();
#pragma unroll
      for (int off = 128; off > 0; off >>= 1) {
        if (tid < off) red[tid] += red[tid + off];
        __syncthreads();
      }
      float rinv = __fdividef(1.0f, red[0]);
      // context over s (thread owns dims tid, tid+256)
      float c0 = 0.f, c1 = 0.f;
      const float* mrow = mem + ((size_t)(b << 9) << 9) + tid;
#pragma unroll 4
      for (int s2 = 0; s2 < 512; ++s2) {
        float av = sl[s2];
        c0 = fmaf(av, mrow[(size_t)s2 << 9], c0);
        c1 = fmaf(av, mrow[((size_t)s2 << 9) + 256], c1);
      }
      ctx[tid] = c0 * rinv;
      ctx[tid + 256] = c1 * rinv;
      __syncthreads();
      // attn_new = [h | ctx] @ W_attn (thread owns column a = tid)
      const float* hc = hcur + b;
      const float* wa = Watt + tid;
      float acc = 0.f;
#pragma unroll 8
      for (int k = 0; k < 512; ++k) acc = fmaf(hc[k << 6], wa[k << 8], acc);
#pragma unroll 8
      for (int k = 0; k < 512; ++k) acc = fmaf(ctx[k], wa[(512 + k) << 8], acc);
      attnT[(tid << 6) + b] = acc;
      aall[((size_t)((b << 8) + t) << 8) + tid] = acc;
    }
    gbar(cnt, gen, 128);
  }
}

// ---------------- tiled fp32 GEMM: C[M,N] = A[M,K] @ B[K,N] (+bias) ----------------
// BM=64 BN=128 BK=32; 256 threads; 8x4 micro-tile
template <bool BIAS>
__global__ __launch_bounds__(256) void k_gemm(
    const float* __restrict__ A, int lda, const float* __restrict__ Bm, int ldb,
    const float* __restrict__ bias, float* __restrict__ C, int ldc, int M, int N, int K) {
  __shared__ float As[32][68];
  __shared__ float Bs[32][132];
  int tid = threadIdx.x;
  int mt = blockIdx.y, nt = blockIdx.x;
  int ty = tid >> 5, tx = tid & 31;
  int m0 = ty << 3, n0 = tx << 2;
  int n0g = nt * 128;
  float acc[8][4] = {};
  for (int kt = 0; kt < K; kt += 32) {
    {
      int mrow = tid >> 3;
      int kq = (tid & 7) << 2;
#pragma unroll
      for (int r = 0; r < 2; ++r) {
        int m = mrow + (r << 5);
        float4 av = *(const float4*)(A + (size_t)(mt * 64 + m) * lda + kt + kq);
        As[kq + 0][m] = av.x; As[kq + 1][m] = av.y;
        As[kq + 2][m] = av.z; As[kq + 3][m] = av.w;
      }
    }
    {
#pragma unroll
      for (int r = 0; r < 4; ++r) {
        int idx = tid + (r << 8);
        int k = idx >> 5, n4 = (idx & 31) << 2;
        int n = n0g + n4;
        float4 bv = make_float4(0.f, 0.f, 0.f, 0.f);
        if (n < N) bv = *(const float4*)(Bm + (size_t)(kt + k) * ldb + n);
        *(float4*)&Bs[k][n4] = bv;
      }
    }
    __syncthreads();
#pragma unroll
    for (int k = 0; k < 32; ++k) {
      float4 a0 = *(const float4*)&As[k][m0];
      float4 a1 = *(const float4*)&As[k][m0 + 4];
      float4 bv = *(const float4*)&Bs[k][n0];
      float am[8] = {a0.x, a0.y, a0.z, a0.w, a1.x, a1.y, a1.z, a1.w};
      float bn[4] = {bv.x, bv.y, bv.z, bv.w};
#pragma unroll
      for (int i = 0; i < 8; ++i)
#pragma unroll
        for (int j = 0; j < 4; ++j) acc[i][j] = fmaf(am[i], bn[j], acc[i][j]);
    }
    __syncthreads();
  }
  int n = n0g + n0;
  if (n < N) {
    float4 bs = make_float4(0.f, 0.f, 0.f, 0.f);
    if (BIAS) bs = *(const float4*)(bias + n);
#pragma unroll
    for (int i = 0; i < 8; ++i) {
      int m = mt * 64 + m0 + i;
      float4 v = make_float4(acc[i][0] + bs.x, acc[i][1] + bs.y,
                             acc[i][2] + bs.z, acc[i][3] + bs.w);
      *(float4*)(C + (size_t)m * ldc + n) = v;
    }
  }
}

// ---------------- host launcher ----------------
extern "C" void kernel_launch(void* const* d_in, const int* in_sizes, int n_in,
                              void* d_out, int out_size, void* d_ws, size_t ws_size,
                              hipStream_t stream) {
  const int* enc_idx = (const int*)d_in[0];
  const int* dec_idx = (const int*)d_in[1];
  const float* E  = (const float*)d_in[2];
  const float* Wf = (const float*)d_in[3];
  const float* bf = (const float*)d_in[4];
  const float* Wb = (const float*)d_in[5];
  const float* bb = (const float*)d_in[6];
  const float* Wd = (const float*)d_in[7];
  const float* bd = (const float*)d_in[8];
  const float* Wk = (const float*)d_in[9];
  const float* Wq = (const float*)d_in[10];
  const float* va = (const float*)d_in[11];
  const float* Wa = (const float*)d_in[12];
  const float* Wp = (const float*)d_in[13];
  const float* bp = (const float*)d_in[14];
  float* out = (float*)d_out;
  float* ws = (float*)d_ws;
  // (needs ws_size >= WS_FLOATS*4 ≈ 169 MB)

  hipMemsetAsync(ws, 0, SMALL_END * sizeof(float), stream);
  k_gatherT<<<TXc * 64, 256, 0, stream>>>(enc_idx, E, ws + OFF_ENCT, TXc);
  k_gatherT<<<TYc * 64, 256, 0, stream>>>(dec_idx, E, ws + OFF_DECT, TYc);
  k_encoder<<<128, 256, 0, stream>>>(ws + OFF_ENCT, Wf, bf, Wb, bb, ws);
  k_gemm<false><<<dim3(2, 512), 256, 0, stream>>>(ws + OFF_MEM, 512, Wk, 256, nullptr,
                                                  ws + OFF_KEYS, 256, 32768, 256, 512);
  k_decoder<<<128, 256, 0, stream>>>(ws + OFF_DECT, Wd, bd, Wq, va, Wa, ws + OFF_KEYS, ws);
  k_gemm<true><<<dim3(79, 256), 256, 0, stream>>>(ws + OFF_AALL, 256, Wp, 10000, bp,
                                                  out, 10000, 16384, 10000, 256);
}